// Round 3
// baseline (504.682 us; speedup 1.0000x reference)
//
#include <hip/hip_runtime.h>
#include <stdint.h>

typedef unsigned int u32;

// ---------- CSR build ----------
__global__ void k_hist_nnz(const int* __restrict__ ni, const int* __restrict__ ei,
                           int* __restrict__ deg_e, int* __restrict__ deg_n, int nnz) {
    int j = blockIdx.x * blockDim.x + threadIdx.x;
    if (j < nnz) {
        atomicAdd(&deg_e[ei[j]], 1);
        atomicAdd(&deg_n[ni[j]], 1);
    }
}

__global__ void k_hist_comp(const int* __restrict__ nc_c, const int* __restrict__ ec_c,
                            int* __restrict__ cnt_cn, int* __restrict__ cnt_ce, int n, int e) {
    int j = blockIdx.x * blockDim.x + threadIdx.x;
    if (j < n) atomicAdd(&cnt_cn[nc_c[j]], 1);
    else if (j < n + e) atomicAdd(&cnt_ce[ec_c[j - n]], 1);
}

__device__ void scan_body(const int* __restrict__ cnt, int* __restrict__ off,
                          int* __restrict__ cur, int n) {
    __shared__ int wsum[16];
    int t = threadIdx.x, lane = t & 63, w = t >> 6;
    int carry = 0;
    for (int base = 0; base < n; base += 8192) {
        int vals[8];
        int i0 = base + t * 8;
        int s = 0;
#pragma unroll
        for (int i = 0; i < 8; ++i) { int idx = i0 + i; int v = (idx < n) ? cnt[idx] : 0; vals[i] = v; s += v; }
        int isc = s;
        for (int d = 1; d < 64; d <<= 1) { int u = __shfl_up(isc, d, 64); if (lane >= d) isc += u; }
        if (lane == 63) wsum[w] = isc;
        __syncthreads();
        if (w == 0 && lane < 16) {
            int x = wsum[lane];
            for (int d = 1; d < 16; d <<= 1) { int u = __shfl_up(x, d, 64); if (lane >= d) x += u; }
            wsum[lane] = x;
        }
        __syncthreads();
        int wbase = (w > 0) ? wsum[w - 1] : 0;
        int excl = carry + wbase + (isc - s);
#pragma unroll
        for (int i = 0; i < 8; ++i) {
            int idx = i0 + i;
            if (idx < n) { off[idx] = excl; cur[idx] = excl; }
            excl += vals[i];
        }
        carry += wsum[15];
        __syncthreads();
    }
    if (t == 0) off[n] = carry;
}

__global__ __launch_bounds__(1024) void k_scan4(
        const int* c0, int* o0, int* u0, int n0,
        const int* c1, int* o1, int* u1, int n1,
        const int* c2, int* o2, int* u2, int n2,
        const int* c3, int* o3, int* u3, int n3) {
    switch (blockIdx.x) {
        case 0: scan_body(c0, o0, u0, n0); break;
        case 1: scan_body(c1, o1, u1, n1); break;
        case 2: scan_body(c2, o2, u2, n2); break;
        default: scan_body(c3, o3, u3, n3); break;
    }
}

__global__ void k_scatter_nnz(const int* __restrict__ ni, const int* __restrict__ ei,
                              int* __restrict__ cur_e, int* __restrict__ cur_n,
                              int* __restrict__ csr_e, int* __restrict__ csr_n, int nnz) {
    int j = blockIdx.x * blockDim.x + threadIdx.x;
    if (j < nnz) {
        int v = ni[j], e = ei[j];
        int p = atomicAdd(&cur_e[e], 1); csr_e[p] = v;   // edge -> member node ids
        int q = atomicAdd(&cur_n[v], 1); csr_n[q] = e;   // node -> incident edge ids
    }
}

__global__ void k_scatter_comp(const int* __restrict__ nc_n, const int* __restrict__ nc_c,
                               const int* __restrict__ ec_e, const int* __restrict__ ec_c,
                               int* __restrict__ cur_cn, int* __restrict__ cur_ce,
                               int* __restrict__ csr_cn, int* __restrict__ csr_ce, int n, int e) {
    int j = blockIdx.x * blockDim.x + threadIdx.x;
    if (j < n) {
        int c = nc_c[j]; int p = atomicAdd(&cur_cn[c], 1); csr_cn[p] = nc_n[j];
    } else if (j < n + e) {
        int jj = j - n;
        int c = ec_c[jj]; int p = atomicAdd(&cur_ce[c], 1); csr_ce[p] = ec_e[jj];
    }
}

// ---------- segment mean (wave per segment, float2 per lane, rows of 128 fp32) ----------
__global__ void k_agg_seg(const float* __restrict__ in, const int* __restrict__ items,
                          const int* __restrict__ off, float* __restrict__ out,
                          int nseg, int nrows, int do_prelu, const float* __restrict__ alpha_p) {
    int seg  = blockIdx.x * (blockDim.x >> 6) + (threadIdx.x >> 6);
    int lane = threadIdx.x & 63;
    if (seg >= nseg) return;
    const float2* inp = (const float2*)in;   // row r = 64 float2s at r*64
    int s0 = off[seg], s1 = off[seg + 1];
    float a0 = 0.f, a1 = 0.f;
    int p = s0;
    for (; p + 4 <= s1; p += 4) {
        u32 r0 = (u32)items[p],     r1 = (u32)items[p + 1];
        u32 r2 = (u32)items[p + 2], r3 = (u32)items[p + 3];
        r0 = (r0 < (u32)nrows) ? r0 : 0u;  r1 = (r1 < (u32)nrows) ? r1 : 0u;
        r2 = (r2 < (u32)nrows) ? r2 : 0u;  r3 = (r3 < (u32)nrows) ? r3 : 0u;
        float2 v0 = inp[((size_t)r0 << 6) + lane];
        float2 v1 = inp[((size_t)r1 << 6) + lane];
        float2 v2 = inp[((size_t)r2 << 6) + lane];
        float2 v3 = inp[((size_t)r3 << 6) + lane];
        a0 += v0.x + v1.x + v2.x + v3.x;
        a1 += v0.y + v1.y + v2.y + v3.y;
    }
    for (; p < s1; ++p) {
        u32 r = (u32)items[p];
        r = (r < (u32)nrows) ? r : 0u;
        float2 v = inp[((size_t)r << 6) + lane];
        a0 += v.x; a1 += v.y;
    }
    float inv = 1.f / fmaxf((float)(s1 - s0), 1.f);
    a0 *= inv; a1 *= inv;
    if (do_prelu) {
        float al = *alpha_p;
        a0 = (a0 >= 0.f) ? a0 : al * a0;
        a1 = (a1 >= 0.f) ? a1 : al * a1;
    }
    float2 r2v; r2v.x = a0; r2v.y = a1;
    ((float2*)out)[((size_t)seg << 6) + lane] = r2v;
}

// ---------- GEMM: [M,128] @ [128,128] fp32, 64x64 tile per block ----------
// Optional second (A2,W2) pair accumulated into the same tile.
// out_raw = plain result, out_act = prelu(result); either may be null.
__global__ __launch_bounds__(256) void k_gemm128(
        const float* __restrict__ A,  const float* __restrict__ W,
        const float* __restrict__ A2, const float* __restrict__ W2,
        float* __restrict__ out_raw, float* __restrict__ out_act,
        int M, const float* __restrict__ alpha_p) {
    __shared__ float As[64 * 128];   // XOR-swizzled k index (swizzle multiple of 4)
    __shared__ float Ws[128 * 64];
    int t  = threadIdx.x;
    int rb = blockIdx.x * 64;
    int cb = blockIdx.y * 64;
    int cg = t & 7, rg = t >> 3;      // cols cg*8..+7, rows rg and rg+32
    int c0 = cg * 8;
    int sw = (rg & 7) << 2;

    float acc[16];
#pragma unroll
    for (int i = 0; i < 16; ++i) acc[i] = 0.f;

    int npair = (A2 != nullptr) ? 2 : 1;
    for (int pair = 0; pair < npair; ++pair) {
        const float* Ap = pair ? A2 : A;
        const float* Wp = pair ? W2 : W;
        if (pair) __syncthreads();
        // stage A tile: 64 rows x 128 k, float4, swizzled (swr multiple of 4)
        for (int i = t; i < 64 * 32; i += 256) {
            int r = i >> 5, dc = i & 31;
            int row = rb + r;
            float4 v = make_float4(0.f, 0.f, 0.f, 0.f);
            if (row < M) v = *(const float4*)(Ap + ((size_t)row << 7) + dc * 4);
            int swr = (r & 7) << 2;
            *(float4*)&As[r * 128 + ((dc * 4) ^ swr)] = v;
        }
        // stage W cols [cb, cb+64)
        for (int i = t; i < 128 * 16; i += 256) {
            int k = i >> 4, dc = i & 15;
            *(float4*)&Ws[k * 64 + dc * 4] = *(const float4*)(Wp + ((size_t)k << 7) + cb + dc * 4);
        }
        __syncthreads();
#pragma unroll 4
        for (int k = 0; k < 128; ++k) {
            float a0 = As[rg * 128 + (k ^ sw)];
            float a1 = As[(rg + 32) * 128 + (k ^ sw)];
            const float* wr = &Ws[k * 64 + c0];
            float4 w0 = *(const float4*)(wr);
            float4 w1 = *(const float4*)(wr + 4);
            acc[0]  += a0 * w0.x; acc[1]  += a0 * w0.y; acc[2]  += a0 * w0.z; acc[3]  += a0 * w0.w;
            acc[4]  += a0 * w1.x; acc[5]  += a0 * w1.y; acc[6]  += a0 * w1.z; acc[7]  += a0 * w1.w;
            acc[8]  += a1 * w0.x; acc[9]  += a1 * w0.y; acc[10] += a1 * w0.z; acc[11] += a1 * w0.w;
            acc[12] += a1 * w1.x; acc[13] += a1 * w1.y; acc[14] += a1 * w1.z; acc[15] += a1 * w1.w;
        }
    }

    float al = *alpha_p;
#pragma unroll
    for (int h = 0; h < 2; ++h) {
        int row = rb + rg + h * 32;
        if (row >= M) continue;
        size_t ob = ((size_t)row << 7) + cb + c0;
        if (out_raw) {
            *(float4*)(out_raw + ob)     = make_float4(acc[h*8+0], acc[h*8+1], acc[h*8+2], acc[h*8+3]);
            *(float4*)(out_raw + ob + 4) = make_float4(acc[h*8+4], acc[h*8+5], acc[h*8+6], acc[h*8+7]);
        }
        if (out_act) {
            float v[8];
#pragma unroll
            for (int jj = 0; jj < 8; ++jj) { float x = acc[h*8+jj]; v[jj] = (x >= 0.f) ? x : al * x; }
            *(float4*)(out_act + ob)     = make_float4(v[0], v[1], v[2], v[3]);
            *(float4*)(out_act + ob + 4) = make_float4(v[4], v[5], v[6], v[7]);
        }
    }
}

extern "C" void kernel_launch(void* const* d_in, const int* in_sizes, int n_in,
                              void* d_out, int out_size, void* d_ws, size_t ws_size,
                              hipStream_t stream) {
    const int N   = in_sizes[0] / 128;   // 50000
    const int NNZ = in_sizes[1] / 2;     // 400000
    const int E   = in_sizes[2] / 2;     // 10000
    const int C   = 500;                 // num_components (fixed by setup)

    const float* x0 = (const float*)d_in[0];
    const int* ni   = (const int*)d_in[1];
    const int* ei   = ni + NNZ;
    const int* ec_e = (const int*)d_in[2];
    const int* ec_c = ec_e + E;
    const int* nc_n = (const int*)d_in[3];
    const int* nc_c = nc_n + N;
    const float* Wne0 = (const float*)d_in[7];
    const float* Wen0 = (const float*)d_in[8];
    const float* Wne1 = (const float*)d_in[11];
    const float* Wen1 = (const float*)d_in[12];
    const float* Wec1 = (const float*)d_in[13];
    const float* Wnc1 = (const float*)d_in[14];
    const float* alpha = (const float*)d_in[15];

    float* out_x = (float*)d_out;                 // [N,128]
    float* out_e = out_x + (size_t)N * 128;       // [E,128]
    float* out_c = out_e + (size_t)E * 128;       // [C,128]
    float* x1    = out_x;   // overlay: x1 fully consumed before out_x is rewritten

    // ---- carve workspace (~20 MB) ----
    char* w = (char*)d_ws;
    auto alloc = [&](size_t bytes) { char* p = w; w += (bytes + 255) & ~(size_t)255; return p; };
    int* counters = (int*)alloc((size_t)(E + N + 2 * C) * 4);  // single memset
    int* deg_e  = counters;
    int* deg_n  = counters + E;
    int* cnt_cn = counters + E + N;
    int* cnt_ce = counters + E + N + C;
    int* off_e  = (int*)alloc((size_t)(E + 1) * 4);
    int* off_n  = (int*)alloc((size_t)(N + 1) * 4);
    int* off_cn = (int*)alloc((size_t)(C + 1) * 4);
    int* off_ce = (int*)alloc((size_t)(C + 1) * 4);
    int* cur_e  = (int*)alloc((size_t)E * 4);
    int* cur_n  = (int*)alloc((size_t)N * 4);
    int* cur_cn = (int*)alloc((size_t)C * 4);
    int* cur_ce = (int*)alloc((size_t)C * 4);
    int* csr_e  = (int*)alloc((size_t)NNZ * 4);
    int* csr_n  = (int*)alloc((size_t)NNZ * 4);
    int* csr_cn = (int*)alloc((size_t)N * 4);
    int* csr_ce = (int*)alloc((size_t)E * 4);
    float* xa   = (float*)alloc((size_t)E * 128 * 4);
    float* eact = (float*)alloc((size_t)E * 128 * 4);
    float* y    = (float*)alloc((size_t)E * 128 * 4);
    float* ca_e = (float*)alloc((size_t)C * 128 * 4);
    float* ca_n = (float*)alloc((size_t)C * 128 * 4);

    const int th = 256;
    // ---- CSR build ----
    hipMemsetAsync(counters, 0, (size_t)(E + N + 2 * C) * 4, stream);
    k_hist_nnz<<<(NNZ + th - 1) / th, th, 0, stream>>>(ni, ei, deg_e, deg_n, NNZ);
    k_hist_comp<<<(N + E + th - 1) / th, th, 0, stream>>>(nc_c, ec_c, cnt_cn, cnt_ce, N, E);
    k_scan4<<<4, 1024, 0, stream>>>(deg_e, off_e, cur_e, E,
                                    deg_n, off_n, cur_n, N,
                                    cnt_cn, off_cn, cur_cn, C,
                                    cnt_ce, off_ce, cur_ce, C);
    k_scatter_nnz<<<(NNZ + th - 1) / th, th, 0, stream>>>(ni, ei, cur_e, cur_n, csr_e, csr_n, NNZ);
    k_scatter_comp<<<(N + E + th - 1) / th, th, 0, stream>>>(nc_n, nc_c, ec_e, ec_c,
                                                             cur_cn, cur_ce, csr_cn, csr_ce, N, E);

    dim3 gE((E + 63) / 64, 2), gC((C + 63) / 64, 2);
    // ---- layer 1 (component path skipped: dead code) ----
    k_agg_seg<<<(E + 3) / 4, 256, 0, stream>>>(x0, csr_e, off_e, xa, E, N, 0, alpha);
    k_gemm128<<<gE, 256, 0, stream>>>(xa, Wne0, nullptr, nullptr, nullptr, eact, E, alpha);
    k_gemm128<<<gE, 256, 0, stream>>>(eact, Wen0, nullptr, nullptr, y, nullptr, E, alpha);
    k_agg_seg<<<(N + 3) / 4, 256, 0, stream>>>(y, csr_n, off_n, x1, N, E, 1, alpha);
    // ---- layer 2 ----
    k_agg_seg<<<(E + 3) / 4, 256, 0, stream>>>(x1, csr_e, off_e, xa, E, N, 0, alpha);
    k_gemm128<<<gE, 256, 0, stream>>>(xa, Wne1, nullptr, nullptr, out_e, eact, E, alpha);
    // components need eact(layer2) and x1 BEFORE out_x overwrite
    k_agg_seg<<<(C + 3) / 4, 256, 0, stream>>>(eact, csr_ce, off_ce, ca_e, C, E, 0, alpha);
    k_agg_seg<<<(C + 3) / 4, 256, 0, stream>>>(x1, csr_cn, off_cn, ca_n, C, N, 0, alpha);
    k_gemm128<<<gC, 256, 0, stream>>>(ca_e, Wec1, ca_n, Wnc1, out_c, nullptr, C, alpha);
    // node path (overwrites out_x = x1 region, reads only y)
    k_gemm128<<<gE, 256, 0, stream>>>(eact, Wen1, nullptr, nullptr, y, nullptr, E, alpha);
    k_agg_seg<<<(N + 3) / 4, 256, 0, stream>>>(y, csr_n, off_n, out_x, N, E, 1, alpha);
}

// Round 4
// 421.929 us; speedup vs baseline: 1.1961x; 1.1961x over previous
//
#include <hip/hip_runtime.h>
#include <stdint.h>

typedef unsigned int u32;
#define TS 4096   // scan tile size (256 thr x 16)

// ---------- histogram (merged: nnz degrees + component counts) ----------
__global__ void k_hist(const int* __restrict__ ni, const int* __restrict__ ei,
                       const int* __restrict__ nc_c, const int* __restrict__ ec_c,
                       int* __restrict__ deg_e, int* __restrict__ deg_n,
                       int* __restrict__ cnt_cn, int* __restrict__ cnt_ce,
                       int nnz, int n, int e) {
    int j = blockIdx.x * blockDim.x + threadIdx.x;
    if (j < nnz) {
        atomicAdd(&deg_e[ei[j]], 1);
        atomicAdd(&deg_n[ni[j]], 1);
    }
    if (j < n) atomicAdd(&cnt_cn[nc_c[j]], 1);
    if (j < e) atomicAdd(&cnt_ce[ec_c[j]], 1);
}

// ---------- 3-phase parallel exclusive scan over 4 arrays ----------
__device__ __forceinline__ void scan_sel(int b, int t0, int t01, int t012,
        const int* c0, int* o0, int* u0, int n0,
        const int* c1, int* o1, int* u1, int n1,
        const int* c2, int* o2, int* u2, int n2,
        const int* c3, int* o3, int* u3, int n3,
        const int*& cnt, int*& off, int*& cur, int& n, int& tile) {
    if (b < t0)        { cnt = c0; off = o0; cur = u0; n = n0; tile = b; }
    else if (b < t01)  { cnt = c1; off = o1; cur = u1; n = n1; tile = b - t0; }
    else if (b < t012) { cnt = c2; off = o2; cur = u2; n = n2; tile = b - t01; }
    else               { cnt = c3; off = o3; cur = u3; n = n3; tile = b - t012; }
}

__global__ void k_scan_p1(const int* c0, int n0, const int* c1, int n1,
                          const int* c2, int n2, const int* c3, int n3,
                          int t0, int t01, int t012, int* __restrict__ tilesum) {
    __shared__ int ws[4];
    int b = blockIdx.x;
    const int* cnt; int* off; int* cur; int n; int tile;
    scan_sel(b, t0, t01, t012, c0, nullptr, nullptr, n0, c1, nullptr, nullptr, n1,
             c2, nullptr, nullptr, n2, c3, nullptr, nullptr, n3, cnt, off, cur, n, tile);
    int base = tile * TS + threadIdx.x * 16;
    int s = 0;
#pragma unroll
    for (int i = 0; i < 16; ++i) { int idx = base + i; if (idx < n) s += cnt[idx]; }
    for (int d = 32; d; d >>= 1) s += __shfl_xor(s, d, 64);
    int lane = threadIdx.x & 63, w = threadIdx.x >> 6;
    if (lane == 0) ws[w] = s;
    __syncthreads();
    if (threadIdx.x == 0) tilesum[b] = ws[0] + ws[1] + ws[2] + ws[3];
}

__global__ void k_scan_p2(const int* __restrict__ tilesum, int* __restrict__ tilebase,
                          int t0, int t01, int t012, int t0123,
                          int* o0, int n0, int* o1, int n1, int* o2, int n2, int* o3, int n3) {
    if (threadIdx.x != 0 || blockIdx.x != 0) return;
    int carry = 0;
    for (int b = 0;    b < t0;    ++b) { tilebase[b] = carry; carry += tilesum[b]; } o0[n0] = carry;
    carry = 0;
    for (int b = t0;   b < t01;   ++b) { tilebase[b] = carry; carry += tilesum[b]; } o1[n1] = carry;
    carry = 0;
    for (int b = t01;  b < t012;  ++b) { tilebase[b] = carry; carry += tilesum[b]; } o2[n2] = carry;
    carry = 0;
    for (int b = t012; b < t0123; ++b) { tilebase[b] = carry; carry += tilesum[b]; } o3[n3] = carry;
}

__global__ void k_scan_p3(const int* c0, int* o0, int* u0, int n0,
                          const int* c1, int* o1, int* u1, int n1,
                          const int* c2, int* o2, int* u2, int n2,
                          const int* c3, int* o3, int* u3, int n3,
                          int t0, int t01, int t012, const int* __restrict__ tilebase) {
    __shared__ int wsum[4];
    int b = blockIdx.x;
    const int* cnt; int* off; int* cur; int n; int tile;
    scan_sel(b, t0, t01, t012, c0, o0, u0, n0, c1, o1, u1, n1,
             c2, o2, u2, n2, c3, o3, u3, n3, cnt, off, cur, n, tile);
    int lane = threadIdx.x & 63, w = threadIdx.x >> 6;
    int base = tile * TS + threadIdx.x * 16;
    int vals[16];
    int s = 0;
#pragma unroll
    for (int i = 0; i < 16; ++i) { int idx = base + i; int v = (idx < n) ? cnt[idx] : 0; vals[i] = v; s += v; }
    int inc = s;
    for (int d = 1; d < 64; d <<= 1) { int u = __shfl_up(inc, d, 64); if (lane >= d) inc += u; }
    if (lane == 63) wsum[w] = inc;
    __syncthreads();
    if (threadIdx.x == 0) {
        int acc = tilebase[b];
        for (int i = 0; i < 4; ++i) { int t = wsum[i]; wsum[i] = acc; acc += t; }
    }
    __syncthreads();
    int ex = wsum[w] + (inc - s);
#pragma unroll
    for (int i = 0; i < 16; ++i) {
        int idx = base + i;
        if (idx < n) { off[idx] = ex; cur[idx] = ex; }
        ex += vals[i];
    }
}

// ---------- scatter (merged) ----------
__global__ void k_scatter(const int* __restrict__ ni, const int* __restrict__ ei,
                          const int* __restrict__ nc_n, const int* __restrict__ nc_c,
                          const int* __restrict__ ec_e, const int* __restrict__ ec_c,
                          int* __restrict__ cur_e, int* __restrict__ cur_n,
                          int* __restrict__ cur_cn, int* __restrict__ cur_ce,
                          int* __restrict__ csr_e, int* __restrict__ csr_n,
                          int* __restrict__ csr_cn, int* __restrict__ csr_ce,
                          int nnz, int n, int e) {
    int j = blockIdx.x * blockDim.x + threadIdx.x;
    if (j < nnz) {
        int v = ni[j], eg = ei[j];
        csr_e[atomicAdd(&cur_e[eg], 1)] = v;
        csr_n[atomicAdd(&cur_n[v], 1)] = eg;
    }
    if (j < n) { int c = nc_c[j]; csr_cn[atomicAdd(&cur_cn[c], 1)] = nc_n[j]; }
    if (j < e) { int c = ec_c[j]; csr_ce[atomicAdd(&cur_ce[c], 1)] = ec_e[j]; }
}

// ---------- segment mean body (wave per segment, float2/lane, 8-deep MLP) ----------
__device__ __forceinline__ void agg_body(const float* __restrict__ in,
                                         const int* __restrict__ items,
                                         const int* __restrict__ off,
                                         float* __restrict__ out,
                                         int nseg, int nrows, int do_prelu,
                                         const float* __restrict__ alpha_p) {
    int seg  = blockIdx.x * (blockDim.x >> 6) + (threadIdx.x >> 6);
    int lane = threadIdx.x & 63;
    if (seg >= nseg) return;
    const float2* inp = (const float2*)in;   // row r = 64 float2s at r*64
    int s0 = off[seg], s1 = off[seg + 1];
    float a0 = 0.f, a1 = 0.f;
    int p = s0;
    for (; p + 8 <= s1; p += 8) {
        u32 r[8];
#pragma unroll
        for (int i = 0; i < 8; ++i) {
            u32 rr = (u32)items[p + i];
            r[i] = (rr < (u32)nrows) ? rr : 0u;
        }
        float2 v[8];
#pragma unroll
        for (int i = 0; i < 8; ++i) v[i] = inp[((size_t)r[i] << 6) + lane];
#pragma unroll
        for (int i = 0; i < 8; ++i) { a0 += v[i].x; a1 += v[i].y; }
    }
    if (p + 4 <= s1) {
        u32 r0 = (u32)items[p], r1 = (u32)items[p+1], r2 = (u32)items[p+2], r3 = (u32)items[p+3];
        r0 = (r0 < (u32)nrows) ? r0 : 0u;  r1 = (r1 < (u32)nrows) ? r1 : 0u;
        r2 = (r2 < (u32)nrows) ? r2 : 0u;  r3 = (r3 < (u32)nrows) ? r3 : 0u;
        float2 v0 = inp[((size_t)r0 << 6) + lane];
        float2 v1 = inp[((size_t)r1 << 6) + lane];
        float2 v2 = inp[((size_t)r2 << 6) + lane];
        float2 v3 = inp[((size_t)r3 << 6) + lane];
        a0 += v0.x + v1.x + v2.x + v3.x;
        a1 += v0.y + v1.y + v2.y + v3.y;
        p += 4;
    }
    for (; p < s1; ++p) {
        u32 r = (u32)items[p];
        r = (r < (u32)nrows) ? r : 0u;
        float2 v = inp[((size_t)r << 6) + lane];
        a0 += v.x; a1 += v.y;
    }
    float inv = 1.f / fmaxf((float)(s1 - s0), 1.f);
    a0 *= inv; a1 *= inv;
    if (do_prelu) {
        float al = *alpha_p;
        a0 = (a0 >= 0.f) ? a0 : al * a0;
        a1 = (a1 >= 0.f) ? a1 : al * a1;
    }
    float2 r2v; r2v.x = a0; r2v.y = a1;
    ((float2*)out)[((size_t)seg << 6) + lane] = r2v;
}

__global__ void k_agg_seg(const float* __restrict__ in, const int* __restrict__ items,
                          const int* __restrict__ off, float* __restrict__ out,
                          int nseg, int nrows, int do_prelu, const float* __restrict__ alpha_p) {
    agg_body(in, items, off, out, nseg, nrows, do_prelu, alpha_p);
}

// dual C-scale aggregation in one launch (blockIdx.y selects descriptor)
__global__ void k_agg_c2(const float* inA, const int* itemsA, const int* offA, float* outA, int nrowsA,
                         const float* inB, const int* itemsB, const int* offB, float* outB, int nrowsB,
                         int nseg) {
    if (blockIdx.y == 0) agg_body(inA, itemsA, offA, outA, nseg, nrowsA, 0, nullptr);
    else                 agg_body(inB, itemsB, offB, outB, nseg, nrowsB, 0, nullptr);
}

// ---------- GEMM: [M,128] @ [128,128] fp32, 64x64 tile per block ----------
__global__ __launch_bounds__(256) void k_gemm128(
        const float* __restrict__ A,  const float* __restrict__ W,
        const float* __restrict__ A2, const float* __restrict__ W2,
        float* __restrict__ out_raw, float* __restrict__ out_act,
        int M, const float* __restrict__ alpha_p) {
    __shared__ float As[64 * 128];   // XOR-swizzled k index (swizzle multiple of 4)
    __shared__ float Ws[128 * 64];
    int t  = threadIdx.x;
    int rb = blockIdx.x * 64;
    int cb = blockIdx.y * 64;
    int cg = t & 7, rg = t >> 3;      // cols cg*8..+7, rows rg and rg+32
    int c0 = cg * 8;
    int sw = (rg & 7) << 2;

    float acc[16];
#pragma unroll
    for (int i = 0; i < 16; ++i) acc[i] = 0.f;

    int npair = (A2 != nullptr) ? 2 : 1;
    for (int pair = 0; pair < npair; ++pair) {
        const float* Ap = pair ? A2 : A;
        const float* Wp = pair ? W2 : W;
        if (pair) __syncthreads();
        for (int i = t; i < 64 * 32; i += 256) {
            int r = i >> 5, dc = i & 31;
            int row = rb + r;
            float4 v = make_float4(0.f, 0.f, 0.f, 0.f);
            if (row < M) v = *(const float4*)(Ap + ((size_t)row << 7) + dc * 4);
            int swr = (r & 7) << 2;
            *(float4*)&As[r * 128 + ((dc * 4) ^ swr)] = v;
        }
        for (int i = t; i < 128 * 16; i += 256) {
            int k = i >> 4, dc = i & 15;
            *(float4*)&Ws[k * 64 + dc * 4] = *(const float4*)(Wp + ((size_t)k << 7) + cb + dc * 4);
        }
        __syncthreads();
#pragma unroll 4
        for (int k = 0; k < 128; ++k) {
            float a0 = As[rg * 128 + (k ^ sw)];
            float a1 = As[(rg + 32) * 128 + (k ^ sw)];
            const float* wr = &Ws[k * 64 + c0];
            float4 w0 = *(const float4*)(wr);
            float4 w1 = *(const float4*)(wr + 4);
            acc[0]  += a0 * w0.x; acc[1]  += a0 * w0.y; acc[2]  += a0 * w0.z; acc[3]  += a0 * w0.w;
            acc[4]  += a0 * w1.x; acc[5]  += a0 * w1.y; acc[6]  += a0 * w1.z; acc[7]  += a0 * w1.w;
            acc[8]  += a1 * w0.x; acc[9]  += a1 * w0.y; acc[10] += a1 * w0.z; acc[11] += a1 * w0.w;
            acc[12] += a1 * w1.x; acc[13] += a1 * w1.y; acc[14] += a1 * w1.z; acc[15] += a1 * w1.w;
        }
    }

    float al = *alpha_p;
#pragma unroll
    for (int h = 0; h < 2; ++h) {
        int row = rb + rg + h * 32;
        if (row >= M) continue;
        size_t ob = ((size_t)row << 7) + cb + c0;
        if (out_raw) {
            *(float4*)(out_raw + ob)     = make_float4(acc[h*8+0], acc[h*8+1], acc[h*8+2], acc[h*8+3]);
            *(float4*)(out_raw + ob + 4) = make_float4(acc[h*8+4], acc[h*8+5], acc[h*8+6], acc[h*8+7]);
        }
        if (out_act) {
            float v[8];
#pragma unroll
            for (int jj = 0; jj < 8; ++jj) { float x = acc[h*8+jj]; v[jj] = (x >= 0.f) ? x : al * x; }
            *(float4*)(out_act + ob)     = make_float4(v[0], v[1], v[2], v[3]);
            *(float4*)(out_act + ob + 4) = make_float4(v[4], v[5], v[6], v[7]);
        }
    }
}

extern "C" void kernel_launch(void* const* d_in, const int* in_sizes, int n_in,
                              void* d_out, int out_size, void* d_ws, size_t ws_size,
                              hipStream_t stream) {
    const int N   = in_sizes[0] / 128;   // 50000
    const int NNZ = in_sizes[1] / 2;     // 400000
    const int E   = in_sizes[2] / 2;     // 10000
    const int C   = 500;                 // num_components (fixed by setup)

    const float* x0 = (const float*)d_in[0];
    const int* ni   = (const int*)d_in[1];
    const int* ei   = ni + NNZ;
    const int* ec_e = (const int*)d_in[2];
    const int* ec_c = ec_e + E;
    const int* nc_n = (const int*)d_in[3];
    const int* nc_c = nc_n + N;
    const float* Wne0 = (const float*)d_in[7];
    const float* Wen0 = (const float*)d_in[8];
    const float* Wne1 = (const float*)d_in[11];
    const float* Wen1 = (const float*)d_in[12];
    const float* Wec1 = (const float*)d_in[13];
    const float* Wnc1 = (const float*)d_in[14];
    const float* alpha = (const float*)d_in[15];

    float* out_x = (float*)d_out;                 // [N,128]
    float* out_e = out_x + (size_t)N * 128;       // [E,128]
    float* out_c = out_e + (size_t)E * 128;       // [C,128]
    float* x1    = out_x;   // overlay: x1 fully consumed before out_x is rewritten

    // ---- carve workspace ----
    char* w = (char*)d_ws;
    auto alloc = [&](size_t bytes) { char* p = w; w += (bytes + 255) & ~(size_t)255; return p; };
    int* counters = (int*)alloc((size_t)(E + N + 2 * C) * 4);  // single memset
    int* deg_e  = counters;
    int* deg_n  = counters + E;
    int* cnt_cn = counters + E + N;
    int* cnt_ce = counters + E + N + C;
    int* off_e  = (int*)alloc((size_t)(E + 1) * 4);
    int* off_n  = (int*)alloc((size_t)(N + 1) * 4);
    int* off_cn = (int*)alloc((size_t)(C + 1) * 4);
    int* off_ce = (int*)alloc((size_t)(C + 1) * 4);
    int* cur_e  = (int*)alloc((size_t)E * 4);
    int* cur_n  = (int*)alloc((size_t)N * 4);
    int* cur_cn = (int*)alloc((size_t)C * 4);
    int* cur_ce = (int*)alloc((size_t)C * 4);
    int* csr_e  = (int*)alloc((size_t)NNZ * 4);
    int* csr_n  = (int*)alloc((size_t)NNZ * 4);
    int* csr_cn = (int*)alloc((size_t)N * 4);
    int* csr_ce = (int*)alloc((size_t)E * 4);
    int* tilesum  = (int*)alloc(64 * 4);
    int* tilebase = (int*)alloc(64 * 4);
    float* xa   = (float*)alloc((size_t)E * 128 * 4);
    float* eact = (float*)alloc((size_t)E * 128 * 4);
    float* y    = (float*)alloc((size_t)E * 128 * 4);
    float* ca_e = (float*)alloc((size_t)C * 128 * 4);
    float* ca_n = (float*)alloc((size_t)C * 128 * 4);

    const int th = 256;
    const int t0 = (E + TS - 1) / TS;         // 3
    const int t1 = (N + TS - 1) / TS;         // 13
    const int t2 = (C + TS - 1) / TS;         // 1
    const int t3 = (C + TS - 1) / TS;         // 1
    const int t01 = t0 + t1, t012 = t01 + t2, t0123 = t012 + t3;

    // ---- CSR build ----
    hipMemsetAsync(counters, 0, (size_t)(E + N + 2 * C) * 4, stream);
    k_hist<<<(NNZ + th - 1) / th, th, 0, stream>>>(ni, ei, nc_c, ec_c,
                                                   deg_e, deg_n, cnt_cn, cnt_ce, NNZ, N, E);
    k_scan_p1<<<t0123, 256, 0, stream>>>(deg_e, E, deg_n, N, cnt_cn, C, cnt_ce, C,
                                         t0, t01, t012, tilesum);
    k_scan_p2<<<1, 64, 0, stream>>>(tilesum, tilebase, t0, t01, t012, t0123,
                                    off_e, E, off_n, N, off_cn, C, off_ce, C);
    k_scan_p3<<<t0123, 256, 0, stream>>>(deg_e, off_e, cur_e, E,
                                         deg_n, off_n, cur_n, N,
                                         cnt_cn, off_cn, cur_cn, C,
                                         cnt_ce, off_ce, cur_ce, C,
                                         t0, t01, t012, tilebase);
    k_scatter<<<(NNZ + th - 1) / th, th, 0, stream>>>(ni, ei, nc_n, nc_c, ec_e, ec_c,
                                                      cur_e, cur_n, cur_cn, cur_ce,
                                                      csr_e, csr_n, csr_cn, csr_ce, NNZ, N, E);

    dim3 gE((E + 63) / 64, 2), gC((C + 63) / 64, 2);
    // ---- layer 1 (component path skipped: dead code) ----
    k_agg_seg<<<(E + 3) / 4, 256, 0, stream>>>(x0, csr_e, off_e, xa, E, N, 0, alpha);
    k_gemm128<<<gE, 256, 0, stream>>>(xa, Wne0, nullptr, nullptr, nullptr, eact, E, alpha);
    k_gemm128<<<gE, 256, 0, stream>>>(eact, Wen0, nullptr, nullptr, y, nullptr, E, alpha);
    k_agg_seg<<<(N + 3) / 4, 256, 0, stream>>>(y, csr_n, off_n, x1, N, E, 1, alpha);
    // ---- layer 2 ----
    k_agg_seg<<<(E + 3) / 4, 256, 0, stream>>>(x1, csr_e, off_e, xa, E, N, 0, alpha);
    k_gemm128<<<gE, 256, 0, stream>>>(xa, Wne1, nullptr, nullptr, out_e, eact, E, alpha);
    // components need eact(layer2) and x1 BEFORE out_x overwrite
    {
        dim3 gC2((C + 3) / 4, 2);
        k_agg_c2<<<gC2, 256, 0, stream>>>(eact, csr_ce, off_ce, ca_e, E,
                                          x1,   csr_cn, off_cn, ca_n, N, C);
    }
    k_gemm128<<<gC, 256, 0, stream>>>(ca_e, Wec1, ca_n, Wnc1, out_c, nullptr, C, alpha);
    // node path (overwrites out_x = x1 region, reads only y)
    k_gemm128<<<gE, 256, 0, stream>>>(eact, Wen1, nullptr, nullptr, y, nullptr, E, alpha);
    k_agg_seg<<<(N + 3) / 4, 256, 0, stream>>>(y, csr_n, off_n, out_x, N, E, 1, alpha);
}

// Round 5
// 415.532 us; speedup vs baseline: 1.2145x; 1.0154x over previous
//
#include <hip/hip_runtime.h>
#include <stdint.h>

typedef unsigned int u32;
#define TS 4096   // scan tile size (256 thr x 16)

// ---------- bf16 helpers ----------
__device__ __forceinline__ float bflo(u32 u) { return __uint_as_float(u << 16); }
__device__ __forceinline__ float bfhi(u32 u) { return __uint_as_float(u & 0xffff0000u); }
__device__ __forceinline__ u32 f2bf(float x) {
    u32 u = __float_as_uint(x);
    return (u + 0x7fffu + ((u >> 16) & 1u)) >> 16;   // RNE
}
__device__ __forceinline__ u32 pack2(float a, float b) { return f2bf(a) | (f2bf(b) << 16); }

// ---------- fp32 -> packed bf16 rows ----------
__global__ void k_cvt_bf(const float2* __restrict__ in, u32* __restrict__ out, int npairs) {
    int j = blockIdx.x * blockDim.x + threadIdx.x;
    if (j < npairs) { float2 v = in[j]; out[j] = pack2(v.x, v.y); }
}

// ---------- histogram (merged) ----------
__global__ void k_hist(const int* __restrict__ ni, const int* __restrict__ ei,
                       const int* __restrict__ nc_c, const int* __restrict__ ec_c,
                       int* __restrict__ deg_e, int* __restrict__ deg_n,
                       int* __restrict__ cnt_cn, int* __restrict__ cnt_ce,
                       int nnz, int n, int e) {
    int j = blockIdx.x * blockDim.x + threadIdx.x;
    if (j < nnz) {
        atomicAdd(&deg_e[ei[j]], 1);
        atomicAdd(&deg_n[ni[j]], 1);
    }
    if (j < n) atomicAdd(&cnt_cn[nc_c[j]], 1);
    if (j < e) atomicAdd(&cnt_ce[ec_c[j]], 1);
}

// ---------- 3-phase parallel exclusive scan over 4 arrays ----------
__device__ __forceinline__ void scan_sel(int b, int t0, int t01, int t012,
        const int* c0, int* o0, int* u0, int n0,
        const int* c1, int* o1, int* u1, int n1,
        const int* c2, int* o2, int* u2, int n2,
        const int* c3, int* o3, int* u3, int n3,
        const int*& cnt, int*& off, int*& cur, int& n, int& tile) {
    if (b < t0)        { cnt = c0; off = o0; cur = u0; n = n0; tile = b; }
    else if (b < t01)  { cnt = c1; off = o1; cur = u1; n = n1; tile = b - t0; }
    else if (b < t012) { cnt = c2; off = o2; cur = u2; n = n2; tile = b - t01; }
    else               { cnt = c3; off = o3; cur = u3; n = n3; tile = b - t012; }
}

__global__ void k_scan_p1(const int* c0, int n0, const int* c1, int n1,
                          const int* c2, int n2, const int* c3, int n3,
                          int t0, int t01, int t012, int* __restrict__ tilesum) {
    __shared__ int ws[4];
    int b = blockIdx.x;
    const int* cnt; int* off; int* cur; int n; int tile;
    scan_sel(b, t0, t01, t012, c0, nullptr, nullptr, n0, c1, nullptr, nullptr, n1,
             c2, nullptr, nullptr, n2, c3, nullptr, nullptr, n3, cnt, off, cur, n, tile);
    int base = tile * TS + threadIdx.x * 16;
    int s = 0;
#pragma unroll
    for (int i = 0; i < 16; ++i) { int idx = base + i; if (idx < n) s += cnt[idx]; }
    for (int d = 32; d; d >>= 1) s += __shfl_xor(s, d, 64);
    int lane = threadIdx.x & 63, w = threadIdx.x >> 6;
    if (lane == 0) ws[w] = s;
    __syncthreads();
    if (threadIdx.x == 0) tilesum[b] = ws[0] + ws[1] + ws[2] + ws[3];
}

__global__ void k_scan_p2(const int* __restrict__ tilesum, int* __restrict__ tilebase,
                          int t0, int t01, int t012, int t0123,
                          int* o0, int n0, int* o1, int n1, int* o2, int n2, int* o3, int n3) {
    if (threadIdx.x != 0 || blockIdx.x != 0) return;
    int carry = 0;
    for (int b = 0;    b < t0;    ++b) { tilebase[b] = carry; carry += tilesum[b]; } o0[n0] = carry;
    carry = 0;
    for (int b = t0;   b < t01;   ++b) { tilebase[b] = carry; carry += tilesum[b]; } o1[n1] = carry;
    carry = 0;
    for (int b = t01;  b < t012;  ++b) { tilebase[b] = carry; carry += tilesum[b]; } o2[n2] = carry;
    carry = 0;
    for (int b = t012; b < t0123; ++b) { tilebase[b] = carry; carry += tilesum[b]; } o3[n3] = carry;
}

__global__ void k_scan_p3(const int* c0, int* o0, int* u0, int n0,
                          const int* c1, int* o1, int* u1, int n1,
                          const int* c2, int* o2, int* u2, int n2,
                          const int* c3, int* o3, int* u3, int n3,
                          int t0, int t01, int t012, const int* __restrict__ tilebase) {
    __shared__ int wsum[4];
    int b = blockIdx.x;
    const int* cnt; int* off; int* cur; int n; int tile;
    scan_sel(b, t0, t01, t012, c0, o0, u0, n0, c1, o1, u1, n1,
             c2, o2, u2, n2, c3, o3, u3, n3, cnt, off, cur, n, tile);
    int lane = threadIdx.x & 63, w = threadIdx.x >> 6;
    int base = tile * TS + threadIdx.x * 16;
    int vals[16];
    int s = 0;
#pragma unroll
    for (int i = 0; i < 16; ++i) { int idx = base + i; int v = (idx < n) ? cnt[idx] : 0; vals[i] = v; s += v; }
    int inc = s;
    for (int d = 1; d < 64; d <<= 1) { int u = __shfl_up(inc, d, 64); if (lane >= d) inc += u; }
    if (lane == 63) wsum[w] = inc;
    __syncthreads();
    if (threadIdx.x == 0) {
        int acc = tilebase[b];
        for (int i = 0; i < 4; ++i) { int t = wsum[i]; wsum[i] = acc; acc += t; }
    }
    __syncthreads();
    int ex = wsum[w] + (inc - s);
#pragma unroll
    for (int i = 0; i < 16; ++i) {
        int idx = base + i;
        if (idx < n) { off[idx] = ex; cur[idx] = ex; }
        ex += vals[i];
    }
}

// ---------- scatter (merged) ----------
__global__ void k_scatter(const int* __restrict__ ni, const int* __restrict__ ei,
                          const int* __restrict__ nc_n, const int* __restrict__ nc_c,
                          const int* __restrict__ ec_e, const int* __restrict__ ec_c,
                          int* __restrict__ cur_e, int* __restrict__ cur_n,
                          int* __restrict__ cur_cn, int* __restrict__ cur_ce,
                          int* __restrict__ csr_e, int* __restrict__ csr_n,
                          int* __restrict__ csr_cn, int* __restrict__ csr_ce,
                          int nnz, int n, int e) {
    int j = blockIdx.x * blockDim.x + threadIdx.x;
    if (j < nnz) {
        int v = ni[j], eg = ei[j];
        csr_e[atomicAdd(&cur_e[eg], 1)] = v;
        csr_n[atomicAdd(&cur_n[v], 1)] = eg;
    }
    if (j < n) { int c = nc_c[j]; csr_cn[atomicAdd(&cur_cn[c], 1)] = nc_n[j]; }
    if (j < e) { int c = ec_c[j]; csr_ce[atomicAdd(&cur_ce[c], 1)] = ec_e[j]; }
}

// ---------- segment mean bodies (wave per segment) ----------
// bf16 input rows (64 u32 per row); optional fp32 and/or bf16 output rows.
__device__ __forceinline__ void agg_bf_body(const u32* __restrict__ in,
                                            const int* __restrict__ items,
                                            const int* __restrict__ off,
                                            float* __restrict__ out_f32,
                                            u32* __restrict__ out_bf,
                                            int nseg, int nrows, int do_prelu,
                                            const float* __restrict__ alpha_p) {
    int seg  = blockIdx.x * (blockDim.x >> 6) + (threadIdx.x >> 6);
    int lane = threadIdx.x & 63;
    if (seg >= nseg) return;
    int s0 = off[seg], s1 = off[seg + 1];
    float a0 = 0.f, a1 = 0.f;
    int p = s0;
    for (; p + 8 <= s1; p += 8) {
        u32 r[8];
#pragma unroll
        for (int i = 0; i < 8; ++i) {
            u32 rr = (u32)items[p + i];
            r[i] = (rr < (u32)nrows) ? rr : 0u;
        }
        u32 v[8];
#pragma unroll
        for (int i = 0; i < 8; ++i) v[i] = in[((size_t)r[i] << 6) + lane];
#pragma unroll
        for (int i = 0; i < 8; ++i) { a0 += bflo(v[i]); a1 += bfhi(v[i]); }
    }
    for (; p < s1; ++p) {
        u32 r = (u32)items[p];
        r = (r < (u32)nrows) ? r : 0u;
        u32 v = in[((size_t)r << 6) + lane];
        a0 += bflo(v); a1 += bfhi(v);
    }
    float inv = 1.f / fmaxf((float)(s1 - s0), 1.f);
    a0 *= inv; a1 *= inv;
    if (do_prelu) {
        float al = *alpha_p;
        a0 = (a0 >= 0.f) ? a0 : al * a0;
        a1 = (a1 >= 0.f) ? a1 : al * a1;
    }
    if (out_f32) {
        float2 rv; rv.x = a0; rv.y = a1;
        ((float2*)out_f32)[((size_t)seg << 6) + lane] = rv;
    }
    if (out_bf) out_bf[((size_t)seg << 6) + lane] = pack2(a0, a1);
}

__device__ __forceinline__ void agg_f32_body(const float* __restrict__ in,
                                             const int* __restrict__ items,
                                             const int* __restrict__ off,
                                             float* __restrict__ out,
                                             int nseg, int nrows) {
    int seg  = blockIdx.x * (blockDim.x >> 6) + (threadIdx.x >> 6);
    int lane = threadIdx.x & 63;
    if (seg >= nseg) return;
    const float2* inp = (const float2*)in;
    int s0 = off[seg], s1 = off[seg + 1];
    float a0 = 0.f, a1 = 0.f;
    for (int p = s0; p < s1; ++p) {
        u32 r = (u32)items[p];
        r = (r < (u32)nrows) ? r : 0u;
        float2 v = inp[((size_t)r << 6) + lane];
        a0 += v.x; a1 += v.y;
    }
    float inv = 1.f / fmaxf((float)(s1 - s0), 1.f);
    float2 rv; rv.x = a0 * inv; rv.y = a1 * inv;
    ((float2*)out)[((size_t)seg << 6) + lane] = rv;
}

__global__ void k_agg_bf(const u32* __restrict__ in, const int* __restrict__ items,
                         const int* __restrict__ off, float* __restrict__ out_f32,
                         u32* __restrict__ out_bf,
                         int nseg, int nrows, int do_prelu, const float* __restrict__ alpha_p) {
    agg_bf_body(in, items, off, out_f32, out_bf, nseg, nrows, do_prelu, alpha_p);
}

// dual C-scale aggregation: y=0 -> fp32 gather (eact), y=1 -> bf16 gather (x1bf)
__global__ void k_agg_c2(const float* inA, const int* itemsA, const int* offA, float* outA, int nrowsA,
                         const u32* inB, const int* itemsB, const int* offB, float* outB, int nrowsB,
                         int nseg) {
    if (blockIdx.y == 0) agg_f32_body(inA, itemsA, offA, outA, nseg, nrowsA);
    else                 agg_bf_body(inB, itemsB, offB, outB, nullptr, nseg, nrowsB, 0, nullptr);
}

// ---------- GEMM: [M,128] @ [128,128] fp32, 64x64 tile per block ----------
// outputs: out_raw (fp32), out_act (fp32, prelu), out_bf (packed bf16 raw) - any may be null
__global__ __launch_bounds__(256) void k_gemm128(
        const float* __restrict__ A,  const float* __restrict__ W,
        const float* __restrict__ A2, const float* __restrict__ W2,
        float* __restrict__ out_raw, float* __restrict__ out_act,
        u32* __restrict__ out_bf,
        int M, const float* __restrict__ alpha_p) {
    __shared__ float As[64 * 128];   // XOR-swizzled k index
    __shared__ float Ws[128 * 64];
    int t  = threadIdx.x;
    int rb = blockIdx.x * 64;
    int cb = blockIdx.y * 64;
    int cg = t & 7, rg = t >> 3;
    int c0 = cg * 8;
    int sw = (rg & 7) << 2;

    float acc[16];
#pragma unroll
    for (int i = 0; i < 16; ++i) acc[i] = 0.f;

    int npair = (A2 != nullptr) ? 2 : 1;
    for (int pair = 0; pair < npair; ++pair) {
        const float* Ap = pair ? A2 : A;
        const float* Wp = pair ? W2 : W;
        if (pair) __syncthreads();
        for (int i = t; i < 64 * 32; i += 256) {
            int r = i >> 5, dc = i & 31;
            int row = rb + r;
            float4 v = make_float4(0.f, 0.f, 0.f, 0.f);
            if (row < M) v = *(const float4*)(Ap + ((size_t)row << 7) + dc * 4);
            int swr = (r & 7) << 2;
            *(float4*)&As[r * 128 + ((dc * 4) ^ swr)] = v;
        }
        for (int i = t; i < 128 * 16; i += 256) {
            int k = i >> 4, dc = i & 15;
            *(float4*)&Ws[k * 64 + dc * 4] = *(const float4*)(Wp + ((size_t)k << 7) + cb + dc * 4);
        }
        __syncthreads();
#pragma unroll 4
        for (int k = 0; k < 128; ++k) {
            float a0 = As[rg * 128 + (k ^ sw)];
            float a1 = As[(rg + 32) * 128 + (k ^ sw)];
            const float* wr = &Ws[k * 64 + c0];
            float4 w0 = *(const float4*)(wr);
            float4 w1 = *(const float4*)(wr + 4);
            acc[0]  += a0 * w0.x; acc[1]  += a0 * w0.y; acc[2]  += a0 * w0.z; acc[3]  += a0 * w0.w;
            acc[4]  += a0 * w1.x; acc[5]  += a0 * w1.y; acc[6]  += a0 * w1.z; acc[7]  += a0 * w1.w;
            acc[8]  += a1 * w0.x; acc[9]  += a1 * w0.y; acc[10] += a1 * w0.z; acc[11] += a1 * w0.w;
            acc[12] += a1 * w1.x; acc[13] += a1 * w1.y; acc[14] += a1 * w1.z; acc[15] += a1 * w1.w;
        }
    }

    float al = *alpha_p;
#pragma unroll
    for (int h = 0; h < 2; ++h) {
        int row = rb + rg + h * 32;
        if (row >= M) continue;
        size_t ob = ((size_t)row << 7) + cb + c0;
        if (out_raw) {
            *(float4*)(out_raw + ob)     = make_float4(acc[h*8+0], acc[h*8+1], acc[h*8+2], acc[h*8+3]);
            *(float4*)(out_raw + ob + 4) = make_float4(acc[h*8+4], acc[h*8+5], acc[h*8+6], acc[h*8+7]);
        }
        if (out_act) {
            float v[8];
#pragma unroll
            for (int jj = 0; jj < 8; ++jj) { float x = acc[h*8+jj]; v[jj] = (x >= 0.f) ? x : al * x; }
            *(float4*)(out_act + ob)     = make_float4(v[0], v[1], v[2], v[3]);
            *(float4*)(out_act + ob + 4) = make_float4(v[4], v[5], v[6], v[7]);
        }
        if (out_bf) {
            // row stride in u32 = 64; this thread covers cols [cb+c0, cb+c0+8) = 4 u32s
            size_t bb = ((size_t)row << 6) + ((cb + c0) >> 1);
            uint4 pk;
            pk.x = pack2(acc[h*8+0], acc[h*8+1]);
            pk.y = pack2(acc[h*8+2], acc[h*8+3]);
            pk.z = pack2(acc[h*8+4], acc[h*8+5]);
            pk.w = pack2(acc[h*8+6], acc[h*8+7]);
            *(uint4*)(out_bf + bb) = pk;
        }
    }
}

extern "C" void kernel_launch(void* const* d_in, const int* in_sizes, int n_in,
                              void* d_out, int out_size, void* d_ws, size_t ws_size,
                              hipStream_t stream) {
    const int N   = in_sizes[0] / 128;   // 50000
    const int NNZ = in_sizes[1] / 2;     // 400000
    const int E   = in_sizes[2] / 2;     // 10000
    const int C   = 500;

    const float* x0 = (const float*)d_in[0];
    const int* ni   = (const int*)d_in[1];
    const int* ei   = ni + NNZ;
    const int* ec_e = (const int*)d_in[2];
    const int* ec_c = ec_e + E;
    const int* nc_n = (const int*)d_in[3];
    const int* nc_c = nc_n + N;
    const float* Wne0 = (const float*)d_in[7];
    const float* Wen0 = (const float*)d_in[8];
    const float* Wne1 = (const float*)d_in[11];
    const float* Wen1 = (const float*)d_in[12];
    const float* Wec1 = (const float*)d_in[13];
    const float* Wnc1 = (const float*)d_in[14];
    const float* alpha = (const float*)d_in[15];

    float* out_x = (float*)d_out;                 // [N,128]
    float* out_e = out_x + (size_t)N * 128;       // [E,128]
    float* out_c = out_e + (size_t)E * 128;       // [C,128]

    // ---- carve workspace ----
    char* w = (char*)d_ws;
    auto alloc = [&](size_t bytes) { char* p = w; w += (bytes + 255) & ~(size_t)255; return p; };
    int* counters = (int*)alloc((size_t)(E + N + 2 * C) * 4);
    int* deg_e  = counters;
    int* deg_n  = counters + E;
    int* cnt_cn = counters + E + N;
    int* cnt_ce = counters + E + N + C;
    int* off_e  = (int*)alloc((size_t)(E + 1) * 4);
    int* off_n  = (int*)alloc((size_t)(N + 1) * 4);
    int* off_cn = (int*)alloc((size_t)(C + 1) * 4);
    int* off_ce = (int*)alloc((size_t)(C + 1) * 4);
    int* cur_e  = (int*)alloc((size_t)E * 4);
    int* cur_n  = (int*)alloc((size_t)N * 4);
    int* cur_cn = (int*)alloc((size_t)C * 4);
    int* cur_ce = (int*)alloc((size_t)C * 4);
    int* csr_e  = (int*)alloc((size_t)NNZ * 4);
    int* csr_n  = (int*)alloc((size_t)NNZ * 4);
    int* csr_cn = (int*)alloc((size_t)N * 4);
    int* csr_ce = (int*)alloc((size_t)E * 4);
    int* tilesum  = (int*)alloc(64 * 4);
    int* tilebase = (int*)alloc(64 * 4);
    u32* xbf  = (u32*)alloc((size_t)N * 64 * 4);    // bf16 x0       (12.8 MB)
    u32* x1bf = (u32*)alloc((size_t)N * 64 * 4);    // bf16 x1       (12.8 MB)
    u32* ybf  = (u32*)alloc((size_t)E * 64 * 4);    // bf16 y        (2.5 MB)
    float* xa   = (float*)alloc((size_t)E * 128 * 4);
    float* eact = (float*)alloc((size_t)E * 128 * 4);
    float* ca_e = (float*)alloc((size_t)C * 128 * 4);
    float* ca_n = (float*)alloc((size_t)C * 128 * 4);

    const int th = 256;
    const int t0 = (E + TS - 1) / TS;
    const int t1 = (N + TS - 1) / TS;
    const int t2 = (C + TS - 1) / TS;
    const int t3 = (C + TS - 1) / TS;
    const int t01 = t0 + t1, t012 = t01 + t2, t0123 = t012 + t3;

    // ---- CSR build + x conversion ----
    hipMemsetAsync(counters, 0, (size_t)(E + N + 2 * C) * 4, stream);
    k_cvt_bf<<<(N * 64 + th - 1) / th, th, 0, stream>>>((const float2*)x0, xbf, N * 64);
    k_hist<<<(NNZ + th - 1) / th, th, 0, stream>>>(ni, ei, nc_c, ec_c,
                                                   deg_e, deg_n, cnt_cn, cnt_ce, NNZ, N, E);
    k_scan_p1<<<t0123, 256, 0, stream>>>(deg_e, E, deg_n, N, cnt_cn, C, cnt_ce, C,
                                         t0, t01, t012, tilesum);
    k_scan_p2<<<1, 64, 0, stream>>>(tilesum, tilebase, t0, t01, t012, t0123,
                                    off_e, E, off_n, N, off_cn, C, off_ce, C);
    k_scan_p3<<<t0123, 256, 0, stream>>>(deg_e, off_e, cur_e, E,
                                         deg_n, off_n, cur_n, N,
                                         cnt_cn, off_cn, cur_cn, C,
                                         cnt_ce, off_ce, cur_ce, C,
                                         t0, t01, t012, tilebase);
    k_scatter<<<(NNZ + th - 1) / th, th, 0, stream>>>(ni, ei, nc_n, nc_c, ec_e, ec_c,
                                                      cur_e, cur_n, cur_cn, cur_ce,
                                                      csr_e, csr_n, csr_cn, csr_ce, NNZ, N, E);

    dim3 gE((E + 63) / 64, 2), gC((C + 63) / 64, 2);
    // ---- layer 1 ----
    k_agg_bf<<<(E + 3) / 4, 256, 0, stream>>>(xbf, csr_e, off_e, xa, nullptr, E, N, 0, alpha);
    k_gemm128<<<gE, 256, 0, stream>>>(xa, Wne0, nullptr, nullptr, nullptr, eact, nullptr, E, alpha);
    k_gemm128<<<gE, 256, 0, stream>>>(eact, Wen0, nullptr, nullptr, nullptr, nullptr, ybf, E, alpha);
    k_agg_bf<<<(N + 3) / 4, 256, 0, stream>>>(ybf, csr_n, off_n, nullptr, x1bf, N, E, 1, alpha);
    // ---- layer 2 ----
    k_agg_bf<<<(E + 3) / 4, 256, 0, stream>>>(x1bf, csr_e, off_e, xa, nullptr, E, N, 0, alpha);
    k_gemm128<<<gE, 256, 0, stream>>>(xa, Wne1, nullptr, nullptr, out_e, eact, nullptr, E, alpha);
    // components (need eact L2 + x1bf)
    {
        dim3 gC2((C + 3) / 4, 2);
        k_agg_c2<<<gC2, 256, 0, stream>>>(eact, csr_ce, off_ce, ca_e, E,
                                          x1bf, csr_cn, off_cn, ca_n, N, C);
    }
    k_gemm128<<<gC, 256, 0, stream>>>(ca_e, Wec1, ca_n, Wnc1, out_c, nullptr, nullptr, C, alpha);
    // node path
    k_gemm128<<<gE, 256, 0, stream>>>(eact, Wen1, nullptr, nullptr, nullptr, nullptr, ybf, E, alpha);
    k_agg_bf<<<(N + 3) / 4, 256, 0, stream>>>(ybf, csr_n, off_n, out_x, nullptr, N, E, 1, alpha);
}

// Round 6
// 396.894 us; speedup vs baseline: 1.2716x; 1.0470x over previous
//
#include <hip/hip_runtime.h>
#include <stdint.h>

typedef unsigned int u32;
#define TS 4096   // scan tile size (256 thr x 16)

// ---------- bf16 helpers ----------
__device__ __forceinline__ float bflo(u32 u) { return __uint_as_float(u << 16); }
__device__ __forceinline__ float bfhi(u32 u) { return __uint_as_float(u & 0xffff0000u); }
__device__ __forceinline__ u32 f2bf(float x) {
    u32 u = __float_as_uint(x);
    return (u + 0x7fffu + ((u >> 16) & 1u)) >> 16;   // RNE
}
__device__ __forceinline__ u32 pack2(float a, float b) { return f2bf(a) | (f2bf(b) << 16); }

// ---------- fused histogram + x->bf16 conversion ----------
__global__ void k_hist_cvt(const float2* __restrict__ x0, u32* __restrict__ xbf, int npairs,
                           const int* __restrict__ ni, const int* __restrict__ ei,
                           const int* __restrict__ nc_c, const int* __restrict__ ec_c,
                           int* __restrict__ deg_e, int* __restrict__ deg_n,
                           int* __restrict__ cnt_cn, int* __restrict__ cnt_ce,
                           int nnz, int n, int e) {
    int j = blockIdx.x * blockDim.x + threadIdx.x;
    if (j < npairs) { float2 v = x0[j]; xbf[j] = pack2(v.x, v.y); }
    if (j < nnz) {
        atomicAdd(&deg_e[ei[j]], 1);
        atomicAdd(&deg_n[ni[j]], 1);
    }
    if (j < n) atomicAdd(&cnt_cn[nc_c[j]], 1);
    if (j < e) atomicAdd(&cnt_ce[ec_c[j]], 1);
}

// ---------- 3-phase parallel exclusive scan over 4 arrays ----------
__device__ __forceinline__ void scan_sel(int b, int t0, int t01, int t012,
        const int* c0, int* o0, int* u0, int n0,
        const int* c1, int* o1, int* u1, int n1,
        const int* c2, int* o2, int* u2, int n2,
        const int* c3, int* o3, int* u3, int n3,
        const int*& cnt, int*& off, int*& cur, int& n, int& tile) {
    if (b < t0)        { cnt = c0; off = o0; cur = u0; n = n0; tile = b; }
    else if (b < t01)  { cnt = c1; off = o1; cur = u1; n = n1; tile = b - t0; }
    else if (b < t012) { cnt = c2; off = o2; cur = u2; n = n2; tile = b - t01; }
    else               { cnt = c3; off = o3; cur = u3; n = n3; tile = b - t012; }
}

__global__ void k_scan_p1(const int* c0, int n0, const int* c1, int n1,
                          const int* c2, int n2, const int* c3, int n3,
                          int t0, int t01, int t012, int* __restrict__ tilesum) {
    __shared__ int ws[4];
    int b = blockIdx.x;
    const int* cnt; int* off; int* cur; int n; int tile;
    scan_sel(b, t0, t01, t012, c0, nullptr, nullptr, n0, c1, nullptr, nullptr, n1,
             c2, nullptr, nullptr, n2, c3, nullptr, nullptr, n3, cnt, off, cur, n, tile);
    int base = tile * TS + threadIdx.x * 16;
    int s = 0;
#pragma unroll
    for (int i = 0; i < 16; ++i) { int idx = base + i; if (idx < n) s += cnt[idx]; }
    for (int d = 32; d; d >>= 1) s += __shfl_xor(s, d, 64);
    int lane = threadIdx.x & 63, w = threadIdx.x >> 6;
    if (lane == 0) ws[w] = s;
    __syncthreads();
    if (threadIdx.x == 0) tilesum[b] = ws[0] + ws[1] + ws[2] + ws[3];
}

__global__ void k_scan_p2(const int* __restrict__ tilesum, int* __restrict__ tilebase,
                          int t0, int t01, int t012, int t0123,
                          int* o0, int n0, int* o1, int n1, int* o2, int n2, int* o3, int n3) {
    if (threadIdx.x != 0 || blockIdx.x != 0) return;
    int carry = 0;
    for (int b = 0;    b < t0;    ++b) { tilebase[b] = carry; carry += tilesum[b]; } o0[n0] = carry;
    carry = 0;
    for (int b = t0;   b < t01;   ++b) { tilebase[b] = carry; carry += tilesum[b]; } o1[n1] = carry;
    carry = 0;
    for (int b = t01;  b < t012;  ++b) { tilebase[b] = carry; carry += tilesum[b]; } o2[n2] = carry;
    carry = 0;
    for (int b = t012; b < t0123; ++b) { tilebase[b] = carry; carry += tilesum[b]; } o3[n3] = carry;
}

__global__ void k_scan_p3(const int* c0, int* o0, int* u0, int n0,
                          const int* c1, int* o1, int* u1, int n1,
                          const int* c2, int* o2, int* u2, int n2,
                          const int* c3, int* o3, int* u3, int n3,
                          int t0, int t01, int t012, const int* __restrict__ tilebase) {
    __shared__ int wsum[4];
    int b = blockIdx.x;
    const int* cnt; int* off; int* cur; int n; int tile;
    scan_sel(b, t0, t01, t012, c0, o0, u0, n0, c1, o1, u1, n1,
             c2, o2, u2, n2, c3, o3, u3, n3, cnt, off, cur, n, tile);
    int lane = threadIdx.x & 63, w = threadIdx.x >> 6;
    int base = tile * TS + threadIdx.x * 16;
    int vals[16];
    int s = 0;
#pragma unroll
    for (int i = 0; i < 16; ++i) { int idx = base + i; int v = (idx < n) ? cnt[idx] : 0; vals[i] = v; s += v; }
    int inc = s;
    for (int d = 1; d < 64; d <<= 1) { int u = __shfl_up(inc, d, 64); if (lane >= d) inc += u; }
    if (lane == 63) wsum[w] = inc;
    __syncthreads();
    if (threadIdx.x == 0) {
        int acc = tilebase[b];
        for (int i = 0; i < 4; ++i) { int t = wsum[i]; wsum[i] = acc; acc += t; }
    }
    __syncthreads();
    int ex = wsum[w] + (inc - s);
#pragma unroll
    for (int i = 0; i < 16; ++i) {
        int idx = base + i;
        if (idx < n) { off[idx] = ex; cur[idx] = ex; }
        ex += vals[i];
    }
}

// ---------- scatter (merged, nontemporal CSR stores) ----------
__global__ void k_scatter(const int* __restrict__ ni, const int* __restrict__ ei,
                          const int* __restrict__ nc_n, const int* __restrict__ nc_c,
                          const int* __restrict__ ec_e, const int* __restrict__ ec_c,
                          int* __restrict__ cur_e, int* __restrict__ cur_n,
                          int* __restrict__ cur_cn, int* __restrict__ cur_ce,
                          int* __restrict__ csr_e, int* __restrict__ csr_n,
                          int* __restrict__ csr_cn, int* __restrict__ csr_ce,
                          int nnz, int n, int e) {
    int j = blockIdx.x * blockDim.x + threadIdx.x;
    if (j < nnz) {
        int v = ni[j], eg = ei[j];
        int p = atomicAdd(&cur_e[eg], 1);
        __builtin_nontemporal_store(v, &csr_e[p]);
        int q = atomicAdd(&cur_n[v], 1);
        __builtin_nontemporal_store(eg, &csr_n[q]);
    }
    if (j < n) { int c = nc_c[j]; int p = atomicAdd(&cur_cn[c], 1);
                 __builtin_nontemporal_store(nc_n[j], &csr_cn[p]); }
    if (j < e) { int c = ec_c[j]; int p = atomicAdd(&cur_ce[c], 1);
                 __builtin_nontemporal_store(ec_e[j], &csr_ce[p]); }
}

// ---------- segment mean: wave per segment, 4 rows per load instruction ----------
// lane = rowslot(2b) x colchunk(4b); each lane loads uint4 = 8 bf16 of its row-quarter.
__device__ __forceinline__ void agg4_body(const u32* __restrict__ in,
                                          const int* __restrict__ items,
                                          const int* __restrict__ off,
                                          float* __restrict__ out_f32,
                                          u32* __restrict__ out_bf,
                                          int nseg, int nrows, int do_prelu,
                                          const float* __restrict__ alpha_p, int seg) {
    int lane = threadIdx.x & 63;
    int rs = lane >> 4;        // row slot 0..3
    int cc = lane & 15;        // col chunk (uint4 index within row)
    if (seg >= nseg) return;
    int s0 = off[seg], s1 = off[seg + 1];
    const uint4* rows = (const uint4*)in;    // row r at rows[r*16 + cc]
    float a[8];
#pragma unroll
    for (int i = 0; i < 8; ++i) a[i] = 0.f;
    int base = s0;
    for (; base + 8 <= s1; base += 8) {
        u32 r0 = (u32)items[base + rs];
        u32 r1 = (u32)items[base + 4 + rs];
        r0 = (r0 < (u32)nrows) ? r0 : 0u;
        r1 = (r1 < (u32)nrows) ? r1 : 0u;
        uint4 v0 = rows[(size_t)r0 * 16 + cc];
        uint4 v1 = rows[(size_t)r1 * 16 + cc];
        a[0] += bflo(v0.x); a[1] += bfhi(v0.x); a[2] += bflo(v0.y); a[3] += bfhi(v0.y);
        a[4] += bflo(v0.z); a[5] += bfhi(v0.z); a[6] += bflo(v0.w); a[7] += bfhi(v0.w);
        a[0] += bflo(v1.x); a[1] += bfhi(v1.x); a[2] += bflo(v1.y); a[3] += bfhi(v1.y);
        a[4] += bflo(v1.z); a[5] += bfhi(v1.z); a[6] += bflo(v1.w); a[7] += bfhi(v1.w);
    }
    int idx = base + rs;
    if (idx < s1) {
        u32 r = (u32)items[idx]; r = (r < (u32)nrows) ? r : 0u;
        uint4 v = rows[(size_t)r * 16 + cc];
        a[0] += bflo(v.x); a[1] += bfhi(v.x); a[2] += bflo(v.y); a[3] += bfhi(v.y);
        a[4] += bflo(v.z); a[5] += bfhi(v.z); a[6] += bflo(v.w); a[7] += bfhi(v.w);
    }
    idx += 4;
    if (idx < s1) {
        u32 r = (u32)items[idx]; r = (r < (u32)nrows) ? r : 0u;
        uint4 v = rows[(size_t)r * 16 + cc];
        a[0] += bflo(v.x); a[1] += bfhi(v.x); a[2] += bflo(v.y); a[3] += bfhi(v.y);
        a[4] += bflo(v.z); a[5] += bfhi(v.z); a[6] += bflo(v.w); a[7] += bfhi(v.w);
    }
    // reduce across the 4 row slots
#pragma unroll
    for (int i = 0; i < 8; ++i) {
        a[i] += __shfl_xor(a[i], 16, 64);
        a[i] += __shfl_xor(a[i], 32, 64);
    }
    float inv = 1.f / fmaxf((float)(s1 - s0), 1.f);
#pragma unroll
    for (int i = 0; i < 8; ++i) a[i] *= inv;
    if (do_prelu) {
        float al = *alpha_p;
#pragma unroll
        for (int i = 0; i < 8; ++i) a[i] = (a[i] >= 0.f) ? a[i] : al * a[i];
    }
    if (rs == 0) {
        if (out_f32) {
            float* o = out_f32 + ((size_t)seg << 7) + cc * 8;
            *(float4*)o       = make_float4(a[0], a[1], a[2], a[3]);
            *(float4*)(o + 4) = make_float4(a[4], a[5], a[6], a[7]);
        }
        if (out_bf) {
            uint4 pk;
            pk.x = pack2(a[0], a[1]); pk.y = pack2(a[2], a[3]);
            pk.z = pack2(a[4], a[5]); pk.w = pack2(a[6], a[7]);
            *(uint4*)(out_bf + ((size_t)seg << 6) + cc * 4) = pk;
        }
    }
}

__global__ void k_agg4(const u32* __restrict__ in, const int* __restrict__ items,
                       const int* __restrict__ off, float* __restrict__ out_f32,
                       u32* __restrict__ out_bf,
                       int nseg, int nrows, int do_prelu, const float* __restrict__ alpha_p) {
    int seg = blockIdx.x * (blockDim.x >> 6) + (threadIdx.x >> 6);
    agg4_body(in, items, off, out_f32, out_bf, nseg, nrows, do_prelu, alpha_p, seg);
}

// dual C-scale aggregation (both bf16 inputs), blockIdx.y selects descriptor
__global__ void k_agg_c2(const u32* inA, const int* itemsA, const int* offA, float* outA, int nrowsA,
                         const u32* inB, const int* itemsB, const int* offB, float* outB, int nrowsB,
                         int nseg) {
    int seg = blockIdx.x * (blockDim.x >> 6) + (threadIdx.x >> 6);
    if (blockIdx.y == 0) agg4_body(inA, itemsA, offA, outA, nullptr, nseg, nrowsA, 0, nullptr, seg);
    else                 agg4_body(inB, itemsB, offB, outB, nullptr, nseg, nrowsB, 0, nullptr, seg);
}

// ---------- fused 2-layer MLP: e = A@W1, act = prelu(e), y = act@W2 ----------
// 32-row tile per block, W staged in 64-col halves. Outputs (nullable):
//   out_raw: fp32 raw e; out_actbf: bf16 act; out_ybf: bf16 y.
__global__ __launch_bounds__(256) void k_mlp(
        const float* __restrict__ A, const float* __restrict__ W1,
        const float* __restrict__ W2,
        float* __restrict__ out_raw, u32* __restrict__ out_actbf,
        u32* __restrict__ out_ybf,
        int M, const float* __restrict__ alpha_p) {
    __shared__ float As[32 * 132];    // +4 pad: rg-stride hits distinct banks
    __shared__ float Ws[128 * 64];
    int t  = threadIdx.x;
    int rb = blockIdx.x * 32;
    int cg = t & 7, rg = t >> 3;      // row rg (0..31), cols cg*8..+8 within half
    int row = rb + rg;

    // stage A tile (32 x 128)
    for (int i = t; i < 32 * 32; i += 256) {
        int r = i >> 5, dc = i & 31;
        int arow = rb + r;
        float4 v = make_float4(0.f, 0.f, 0.f, 0.f);
        if (arow < M) v = *(const float4*)(A + ((size_t)arow << 7) + dc * 4);
        *(float4*)&As[r * 132 + dc * 4] = v;
    }

    float e[2][8];
#pragma unroll
    for (int h = 0; h < 2; ++h) {
        __syncthreads();
        for (int i = t; i < 128 * 16; i += 256) {
            int k = i >> 4, dc = i & 15;
            *(float4*)&Ws[k * 64 + dc * 4] = *(const float4*)(W1 + ((size_t)k << 7) + h * 64 + dc * 4);
        }
        __syncthreads();
        float acc[8];
#pragma unroll
        for (int i = 0; i < 8; ++i) acc[i] = 0.f;
        for (int k = 0; k < 128; ++k) {
            float av = As[rg * 132 + k];
            float4 w0 = *(const float4*)&Ws[k * 64 + cg * 8];
            float4 w1 = *(const float4*)&Ws[k * 64 + cg * 8 + 4];
            acc[0] += av * w0.x; acc[1] += av * w0.y; acc[2] += av * w0.z; acc[3] += av * w0.w;
            acc[4] += av * w1.x; acc[5] += av * w1.y; acc[6] += av * w1.z; acc[7] += av * w1.w;
        }
#pragma unroll
        for (int i = 0; i < 8; ++i) e[h][i] = acc[i];
    }
    __syncthreads();   // all reads of As (xa) done

    float al = *alpha_p;
    // emit raw e / bf16 act; write act into As
    if (row < M && out_raw) {
#pragma unroll
        for (int h = 0; h < 2; ++h) {
            float* o = out_raw + ((size_t)row << 7) + h * 64 + cg * 8;
            *(float4*)o       = make_float4(e[h][0], e[h][1], e[h][2], e[h][3]);
            *(float4*)(o + 4) = make_float4(e[h][4], e[h][5], e[h][6], e[h][7]);
        }
    }
    float act[2][8];
#pragma unroll
    for (int h = 0; h < 2; ++h)
#pragma unroll
        for (int i = 0; i < 8; ++i) { float x = e[h][i]; act[h][i] = (x >= 0.f) ? x : al * x; }
    if (row < M && out_actbf) {
#pragma unroll
        for (int h = 0; h < 2; ++h) {
            uint4 pk;
            pk.x = pack2(act[h][0], act[h][1]); pk.y = pack2(act[h][2], act[h][3]);
            pk.z = pack2(act[h][4], act[h][5]); pk.w = pack2(act[h][6], act[h][7]);
            *(uint4*)(out_actbf + ((size_t)row << 6) + h * 32 + cg * 4) = pk;
        }
    }
#pragma unroll
    for (int h = 0; h < 2; ++h) {
        *(float4*)&As[rg * 132 + h * 64 + cg * 8]     = make_float4(act[h][0], act[h][1], act[h][2], act[h][3]);
        *(float4*)&As[rg * 132 + h * 64 + cg * 8 + 4] = make_float4(act[h][4], act[h][5], act[h][6], act[h][7]);
    }

    float y[2][8];
#pragma unroll
    for (int h = 0; h < 2; ++h) {
        __syncthreads();
        for (int i = t; i < 128 * 16; i += 256) {
            int k = i >> 4, dc = i & 15;
            *(float4*)&Ws[k * 64 + dc * 4] = *(const float4*)(W2 + ((size_t)k << 7) + h * 64 + dc * 4);
        }
        __syncthreads();
        float acc[8];
#pragma unroll
        for (int i = 0; i < 8; ++i) acc[i] = 0.f;
        for (int k = 0; k < 128; ++k) {
            float av = As[rg * 132 + k];
            float4 w0 = *(const float4*)&Ws[k * 64 + cg * 8];
            float4 w1 = *(const float4*)&Ws[k * 64 + cg * 8 + 4];
            acc[0] += av * w0.x; acc[1] += av * w0.y; acc[2] += av * w0.z; acc[3] += av * w0.w;
            acc[4] += av * w1.x; acc[5] += av * w1.y; acc[6] += av * w1.z; acc[7] += av * w1.w;
        }
#pragma unroll
        for (int i = 0; i < 8; ++i) y[h][i] = acc[i];
    }
    if (row < M && out_ybf) {
#pragma unroll
        for (int h = 0; h < 2; ++h) {
            uint4 pk;
            pk.x = pack2(y[h][0], y[h][1]); pk.y = pack2(y[h][2], y[h][3]);
            pk.z = pack2(y[h][4], y[h][5]); pk.w = pack2(y[h][6], y[h][7]);
            *(uint4*)(out_ybf + ((size_t)row << 6) + h * 32 + cg * 4) = pk;
        }
    }
}

// ---------- GEMM for component path: pair-accumulate [C,128]@[128,128] ----------
__global__ __launch_bounds__(256) void k_gemm128(
        const float* __restrict__ A,  const float* __restrict__ W,
        const float* __restrict__ A2, const float* __restrict__ W2,
        float* __restrict__ out_raw,
        int M, const float* __restrict__ alpha_p) {
    __shared__ float As[64 * 128];
    __shared__ float Ws[128 * 64];
    int t  = threadIdx.x;
    int rb = blockIdx.x * 64;
    int cb = blockIdx.y * 64;
    int cg = t & 7, rg = t >> 3;
    int c0 = cg * 8;
    int sw = (rg & 7) << 2;

    float acc[16];
#pragma unroll
    for (int i = 0; i < 16; ++i) acc[i] = 0.f;

    for (int pair = 0; pair < 2; ++pair) {
        const float* Ap = pair ? A2 : A;
        const float* Wp = pair ? W2 : W;
        if (pair) __syncthreads();
        for (int i = t; i < 64 * 32; i += 256) {
            int r = i >> 5, dc = i & 31;
            int row = rb + r;
            float4 v = make_float4(0.f, 0.f, 0.f, 0.f);
            if (row < M) v = *(const float4*)(Ap + ((size_t)row << 7) + dc * 4);
            int swr = (r & 7) << 2;
            *(float4*)&As[r * 128 + ((dc * 4) ^ swr)] = v;
        }
        for (int i = t; i < 128 * 16; i += 256) {
            int k = i >> 4, dc = i & 15;
            *(float4*)&Ws[k * 64 + dc * 4] = *(const float4*)(Wp + ((size_t)k << 7) + cb + dc * 4);
        }
        __syncthreads();
#pragma unroll 4
        for (int k = 0; k < 128; ++k) {
            float a0 = As[rg * 128 + (k ^ sw)];
            float a1 = As[(rg + 32) * 128 + (k ^ sw)];
            const float* wr = &Ws[k * 64 + c0];
            float4 w0 = *(const float4*)(wr);
            float4 w1 = *(const float4*)(wr + 4);
            acc[0]  += a0 * w0.x; acc[1]  += a0 * w0.y; acc[2]  += a0 * w0.z; acc[3]  += a0 * w0.w;
            acc[4]  += a0 * w1.x; acc[5]  += a0 * w1.y; acc[6]  += a0 * w1.z; acc[7]  += a0 * w1.w;
            acc[8]  += a1 * w0.x; acc[9]  += a1 * w0.y; acc[10] += a1 * w0.z; acc[11] += a1 * w0.w;
            acc[12] += a1 * w1.x; acc[13] += a1 * w1.y; acc[14] += a1 * w1.z; acc[15] += a1 * w1.w;
        }
    }
#pragma unroll
    for (int h = 0; h < 2; ++h) {
        int row = rb + rg + h * 32;
        if (row >= M) continue;
        size_t ob = ((size_t)row << 7) + cb + c0;
        *(float4*)(out_raw + ob)     = make_float4(acc[h*8+0], acc[h*8+1], acc[h*8+2], acc[h*8+3]);
        *(float4*)(out_raw + ob + 4) = make_float4(acc[h*8+4], acc[h*8+5], acc[h*8+6], acc[h*8+7]);
    }
}

extern "C" void kernel_launch(void* const* d_in, const int* in_sizes, int n_in,
                              void* d_out, int out_size, void* d_ws, size_t ws_size,
                              hipStream_t stream) {
    const int N   = in_sizes[0] / 128;   // 50000
    const int NNZ = in_sizes[1] / 2;     // 400000
    const int E   = in_sizes[2] / 2;     // 10000
    const int C   = 500;

    const float* x0 = (const float*)d_in[0];
    const int* ni   = (const int*)d_in[1];
    const int* ei   = ni + NNZ;
    const int* ec_e = (const int*)d_in[2];
    const int* ec_c = ec_e + E;
    const int* nc_n = (const int*)d_in[3];
    const int* nc_c = nc_n + N;
    const float* Wne0 = (const float*)d_in[7];
    const float* Wen0 = (const float*)d_in[8];
    const float* Wne1 = (const float*)d_in[11];
    const float* Wen1 = (const float*)d_in[12];
    const float* Wec1 = (const float*)d_in[13];
    const float* Wnc1 = (const float*)d_in[14];
    const float* alpha = (const float*)d_in[15];

    float* out_x = (float*)d_out;                 // [N,128]
    float* out_e = out_x + (size_t)N * 128;       // [E,128]
    float* out_c = out_e + (size_t)E * 128;       // [C,128]

    // ---- carve workspace ----
    char* w = (char*)d_ws;
    auto alloc = [&](size_t bytes) { char* p = w; w += (bytes + 255) & ~(size_t)255; return p; };
    int* counters = (int*)alloc((size_t)(E + N + 2 * C) * 4);
    int* deg_e  = counters;
    int* deg_n  = counters + E;
    int* cnt_cn = counters + E + N;
    int* cnt_ce = counters + E + N + C;
    int* off_e  = (int*)alloc((size_t)(E + 1) * 4);
    int* off_n  = (int*)alloc((size_t)(N + 1) * 4);
    int* off_cn = (int*)alloc((size_t)(C + 1) * 4);
    int* off_ce = (int*)alloc((size_t)(C + 1) * 4);
    int* cur_e  = (int*)alloc((size_t)E * 4);
    int* cur_n  = (int*)alloc((size_t)N * 4);
    int* cur_cn = (int*)alloc((size_t)C * 4);
    int* cur_ce = (int*)alloc((size_t)C * 4);
    int* csr_e  = (int*)alloc((size_t)NNZ * 4);
    int* csr_n  = (int*)alloc((size_t)NNZ * 4);
    int* csr_cn = (int*)alloc((size_t)N * 4);
    int* csr_ce = (int*)alloc((size_t)E * 4);
    int* tilesum  = (int*)alloc(64 * 4);
    int* tilebase = (int*)alloc(64 * 4);
    u32* xbf    = (u32*)alloc((size_t)N * 64 * 4);    // bf16 x0   (12.8 MB)
    u32* x1bf   = (u32*)alloc((size_t)N * 64 * 4);    // bf16 x1   (12.8 MB)
    u32* ybf    = (u32*)alloc((size_t)E * 64 * 4);    // bf16 y    (2.5 MB)
    u32* eactbf = (u32*)alloc((size_t)E * 64 * 4);    // bf16 eact (2.5 MB)
    float* xa   = (float*)alloc((size_t)E * 128 * 4); // fp32 agg  (5.1 MB)
    float* ca_e = (float*)alloc((size_t)C * 128 * 4);
    float* ca_n = (float*)alloc((size_t)C * 128 * 4);

    const int th = 256;
    const int t0 = (E + TS - 1) / TS;
    const int t1 = (N + TS - 1) / TS;
    const int t2 = (C + TS - 1) / TS;
    const int t3 = (C + TS - 1) / TS;
    const int t01 = t0 + t1, t012 = t01 + t2, t0123 = t012 + t3;
    const int npairs = N * 64;

    // ---- CSR build + x conversion ----
    hipMemsetAsync(counters, 0, (size_t)(E + N + 2 * C) * 4, stream);
    k_hist_cvt<<<(npairs + th - 1) / th, th, 0, stream>>>(
        (const float2*)x0, xbf, npairs, ni, ei, nc_c, ec_c,
        deg_e, deg_n, cnt_cn, cnt_ce, NNZ, N, E);
    k_scan_p1<<<t0123, 256, 0, stream>>>(deg_e, E, deg_n, N, cnt_cn, C, cnt_ce, C,
                                         t0, t01, t012, tilesum);
    k_scan_p2<<<1, 64, 0, stream>>>(tilesum, tilebase, t0, t01, t012, t0123,
                                    off_e, E, off_n, N, off_cn, C, off_ce, C);
    k_scan_p3<<<t0123, 256, 0, stream>>>(deg_e, off_e, cur_e, E,
                                         deg_n, off_n, cur_n, N,
                                         cnt_cn, off_cn, cur_cn, C,
                                         cnt_ce, off_ce, cur_ce, C,
                                         t0, t01, t012, tilebase);
    k_scatter<<<(NNZ + th - 1) / th, th, 0, stream>>>(ni, ei, nc_n, nc_c, ec_e, ec_c,
                                                      cur_e, cur_n, cur_cn, cur_ce,
                                                      csr_e, csr_n, csr_cn, csr_ce, NNZ, N, E);

    const int gmlp = (E + 31) / 32;   // 313
    // ---- layer 1 ----
    k_agg4<<<(E + 3) / 4, 256, 0, stream>>>(xbf, csr_e, off_e, xa, nullptr, E, N, 0, alpha);
    k_mlp<<<gmlp, 256, 0, stream>>>(xa, Wne0, Wen0, nullptr, nullptr, ybf, E, alpha);
    k_agg4<<<(N + 3) / 4, 256, 0, stream>>>(ybf, csr_n, off_n, nullptr, x1bf, N, E, 1, alpha);
    // ---- layer 2 ----
    k_agg4<<<(E + 3) / 4, 256, 0, stream>>>(x1bf, csr_e, off_e, xa, nullptr, E, N, 0, alpha);
    k_mlp<<<gmlp, 256, 0, stream>>>(xa, Wne1, Wen1, out_e, eactbf, ybf, E, alpha);
    // ---- components ----
    {
        dim3 gC2((C + 3) / 4, 2);
        k_agg_c2<<<gC2, 256, 0, stream>>>(eactbf, csr_ce, off_ce, ca_e, E,
                                          x1bf,   csr_cn, off_cn, ca_n, N, C);
    }
    {
        dim3 gC((C + 63) / 64, 2);
        k_gemm128<<<gC, 256, 0, stream>>>(ca_e, Wec1, ca_n, Wnc1, out_c, C, alpha);
    }
    // ---- node output ----
    k_agg4<<<(N + 3) / 4, 256, 0, stream>>>(ybf, csr_n, off_n, out_x, nullptr, N, E, 1, alpha);
}